// Round 11
// baseline (469.781 us; speedup 1.0000x reference)
//
#include <hip/hip_runtime.h>

typedef __bf16 bf16x8 __attribute__((ext_vector_type(8)));
typedef float f32x16 __attribute__((ext_vector_type(16)));
typedef unsigned int u32x4 __attribute__((ext_vector_type(4)));

// ---------------- sizes ----------------
// B=8, LAT=512, CIN=F=256, Hin=Win=64, H=W=128, K=3
// ws layout (bytes):
//   xu_p NHWC bf16 [8][130][130][256] : off 0          size 69222400
//   y1_p NHWC bf16 [8][130][130][256] : off 69222400   size 69222400
//   wm   bf16 [8][256][9][256]        : off 138444800  size 9437184   (reused)
//   sbuf f32 [2][8][256]              : off 147881984  size 16384

#define GLDS(gsrc, ldst) __builtin_amdgcn_global_load_lds( \
    (const __attribute__((address_space(1))) unsigned int*)(gsrc), \
    (__attribute__((address_space(3))) unsigned int*)(ldst), 16, 0, 0)

#define MFMA32(a, b, c) __builtin_amdgcn_mfma_f32_32x32x16_bf16((a), (b), (c), 0, 0, 0)

// ---------------- styles ----------------
__global__ void style_kernel(const float* __restrict__ istyle,
                             const float* __restrict__ ws1, const float* __restrict__ bs1,
                             const float* __restrict__ ws2, const float* __restrict__ bs2,
                             float* __restrict__ sbuf) {
    int b = blockIdx.x;
    int which = blockIdx.y;
    int c = threadIdx.x;
    const float* ws = which ? ws2 : ws1;
    const float* bs = which ? bs2 : bs1;
    __shared__ float st[512];
    for (int i = threadIdx.x; i < 512; i += 256) st[i] = istyle[b * 512 + i];
    __syncthreads();
    float acc = bs[c];
    const float* wr = ws + (size_t)c * 512;
    for (int l = 0; l < 512; ++l) acc += st[l] * wr[l];
    sbuf[((size_t)which * 8 + b) * 256 + c] = acc;
}

// ---------------- modulate + demodulate -> bf16 [b][o][tap][c] ----------------
__global__ void modw_kernel(const float* __restrict__ w, const float* __restrict__ s,
                            __bf16* __restrict__ wm) {
    int wv = threadIdx.x >> 6, lane = threadIdx.x & 63;
    int idx = blockIdx.x * 4 + wv;      // 0..2047
    int b = idx >> 8, o = idx & 255;
    int c0 = lane * 4;
    const float* wr = w + ((size_t)o * 256 + c0) * 9;
    const float* sb = s + (size_t)b * 256 + c0;
    float v[36];
    float ss = 0.f;
#pragma unroll
    for (int cc = 0; cc < 4; ++cc) {
        float sm = sb[cc] + 1.0f;
#pragma unroll
        for (int t = 0; t < 9; ++t) {
            float x = wr[cc * 9 + t] * sm;
            v[cc * 9 + t] = x;
            ss += x * x;
        }
    }
#pragma unroll
    for (int off = 32; off > 0; off >>= 1) ss += __shfl_xor(ss, off);
    float d = rsqrtf(ss + 1e-8f);
    __bf16* wp = wm + ((size_t)(b * 256 + o) * 9) * 256 + c0;
#pragma unroll
    for (int t = 0; t < 9; ++t) {
        union { __bf16 h[4]; uint2 u; } pk;
#pragma unroll
        for (int cc = 0; cc < 4; ++cc) pk.h[cc] = (__bf16)(v[cc * 9 + t] * d);
        *(uint2*)(wp + (size_t)t * 256) = pk.u;
    }
}

// ---------------- zero the 1-pixel border ----------------
__global__ void zeropad_kernel(__bf16* __restrict__ xu, __bf16* __restrict__ y1) {
    int p0 = blockIdx.x * 8;
    int b  = blockIdx.y;
    __bf16* buf = blockIdx.z ? y1 : xu;
    int p = p0 + (threadIdx.x >> 5);
    if (p >= 516) return;
    int chunk = threadIdx.x & 31;
    int y, x;
    if (p < 130)      { y = 0;           x = p; }
    else if (p < 260) { y = 129;         x = p - 130; }
    else if (p < 388) { y = p - 260 + 1; x = 0; }
    else              { y = p - 388 + 1; x = 129; }
    uint4 z = make_uint4(0, 0, 0, 0);
    *(uint4*)(buf + (((size_t)b * 130 + y) * 130 + x) * 256 + chunk * 8) = z;
}

// ---------------- bilinear 2x upsample NCHW f32 -> padded NHWC bf16 ----------------
__global__ __launch_bounds__(256) void upsample_kernel(const float* __restrict__ x,
                                                       __bf16* __restrict__ xu) {
    int y = blockIdx.x;   // 0..127
    int b = blockIdx.y;   // 0..7
    __shared__ __bf16 orow[128 * 256];   // [px][ch] 64 KB
    int tid = threadIdx.x;

    int j = y >> 1;
    int y0, y1; float wy0, wy1;
    if (y & 1) { y0 = j; y1 = (j + 1 < 64) ? j + 1 : 63; wy0 = 0.75f; wy1 = 0.25f; }
    else       { y0 = (j - 1 >= 0) ? j - 1 : 0; y1 = j; wy0 = 0.25f; wy1 = 0.75f; }

    int c  = tid >> 3;          // 0..31
    int xs = (tid & 7) * 16;
    for (int ct = 0; ct < 8; ++ct) {
        int cc = ct * 32 + c;
        const float* row0 = x + ((size_t)(b * 256 + cc) * 64 + y0) * 64;
        const float* row1 = x + ((size_t)(b * 256 + cc) * 64 + y1) * 64;
#pragma unroll
        for (int k = 0; k < 16; ++k) {
            int xo = xs + k;
            int i = xo >> 1;
            int x0, x1; float wx0, wx1;
            if (xo & 1) { x0 = i; x1 = (i + 1 < 64) ? i + 1 : 63; wx0 = 0.75f; wx1 = 0.25f; }
            else        { x0 = (i - 1 >= 0) ? i - 1 : 0; x1 = i; wx0 = 0.25f; wx1 = 0.75f; }
            float v0 = wx0 * row0[x0] + wx1 * row0[x1];
            float v1 = wx0 * row1[x0] + wx1 * row1[x1];
            orow[xo * 256 + cc] = (__bf16)(wy0 * v0 + wy1 * v1);
        }
    }
    __syncthreads();
    uint4* dst = (uint4*)(xu + (((size_t)(b * 130) + y + 1) * 130 + 1) * 256);
    const uint4* src = (const uint4*)orow;
#pragma unroll
    for (int it = 0; it < 16; ++it)
        dst[it * 256 + tid] = src[it * 256 + tid];
}

// ---------------- implicit-GEMM modulated conv: 128Mx128N, BK=64, 32x32x16 MFMA ----------------
// Per block: batch b, one output row (128 px), 128 out-channels (om).
// 4 waves of 64x64: acc[2][2] f32x16 (64 VGPR). 16 MFMA(32x32x16) per K-tile per wave
// (half the instructions of 16x16x32 at +20% pipe rate; m119: 2495 TF, 8.07cy).
// LDS: A dbuf [2][128][64] 32KB + B dbuf [2][128][64] 32KB = 64KB -> 2 blocks/CU.
// R5-proven single-barrier schedule: STAGE(t+1)->buf^1; 16 ds_read; setprio MFMA;
// vmcnt(0); barrier.  XOR-chunk swizzle (verified 0-conflict).  Compile-time tap loop.
// K-order c0-major/tap-minor (L2-hot staging, R4-verified).  NT epilogue stores.
template <int PHASE>
__global__ __launch_bounds__(256, 2) void conv_kernel(
    const __bf16* __restrict__ in,    // padded NHWC [8][130][130][256]
    const __bf16* __restrict__ wmall, // [8][256][9][256]
    float* __restrict__ outf,
    __bf16* __restrict__ outb) {
    __shared__ __attribute__((aligned(128))) char smem[65536];
    __bf16* const sA = (__bf16*)smem;             // [2][128][64]
    __bf16* const sB = (__bf16*)(smem + 32768);   // [2][128][64]
    const int tid  = threadIdx.x;
    const int bid  = blockIdx.x;
    // XCD-bijective swizzle: 2048 blocks = 8 XCDs x 256; one batch per XCD.
    const int swz  = (bid & 7) * 256 + (bid >> 3);
    const int b    = swz >> 8;
    const int rem  = swz & 255;
    const int yrow = rem >> 1;
    const int om   = (rem & 1) * 128;
    const int lane = tid & 63;
    const int wv   = tid >> 6;          // 0..3
    const int wo   = (wv >> 1) * 64;    // wave M offset within 128
    const int wn   = (wv & 1) * 64;     // wave N offset within 128
    const int l31  = lane & 31;
    const int hi   = lane >> 5;         // k-half
    // staging: lane -> (row r8, chunk), source chunk XOR-pre-swizzled
    const int r8     = lane >> 3;                 // 0..7
    const int chunkS = (lane & 7) ^ (r8 & 7);
    const __bf16* aSrc = wmall + ((size_t)(b * 256 + om) + wv * 32 + r8) * 2304 + chunkS * 8;
    const __bf16* bSrc = in + ((size_t)((b * 130 + yrow) * 130) + wv * 32 + r8) * 256 + chunkS * 8;

    f32x16 acc[2][2] = {};

#define STAGE(TAP, CB, BSEL)                                                    \
    {   const size_t ao_ = (size_t)((TAP) * 256 + (CB) * 64);                   \
        const size_t bo_ = (size_t)((((TAP) / 3) * 130 + ((TAP) % 3)) * 256 + (CB) * 64); \
        __bf16* Ad_ = sA + (BSEL) * 8192 + (wv * 32) * 64;                      \
        __bf16* Bd_ = sB + (BSEL) * 8192 + (wv * 32) * 64;                      \
        _Pragma("unroll")                                                       \
        for (int q = 0; q < 4; ++q) {                                           \
            GLDS(aSrc + ao_ + (size_t)q * 8 * 2304, Ad_ + q * 8 * 64);          \
            GLDS(bSrc + bo_ + (size_t)q * 8 * 256,  Bd_ + q * 8 * 64);          \
        }                                                                       \
    }

    // prologue: stage tile 0 (tap 0, c0=0) into buffer 0
    STAGE(0, 0, 0);
    asm volatile("s_waitcnt vmcnt(0)" ::: "memory");
    __builtin_amdgcn_s_barrier();
    asm volatile("" ::: "memory");

#pragma unroll 1
    for (int cb = 0; cb < 4; ++cb) {
#pragma unroll
        for (int tap = 0; tap < 9; ++tap) {
            const int t   = cb * 9 + tap;          // parity known at compile time per tap
            const int cur = (cb + tap) & 1;
            // stage next tile into the other buffer
            if (t < 35) {
                if (tap < 8) { STAGE(tap + 1, cb, cur ^ 1); }
                else         { STAGE(0, cb + 1, cur ^ 1); }
            }
            // read 16 fragments (8 A + 8 B) from current buffer
            const char* Ab = (const char*)(sA + cur * 8192);
            const char* Bb = (const char*)(sB + cur * 8192);
            bf16x8 af[2][4], bf[2][4];
#pragma unroll
            for (int mi = 0; mi < 2; ++mi) {
                const int ra = wo + mi * 32 + l31;
                const char* ap = Ab + ra * 128;
                const int rb = wn + mi * 32 + l31;
                const char* bp = Bb + rb * 128;
#pragma unroll
                for (int s = 0; s < 4; ++s) {
                    af[mi][s] = *(const bf16x8*)(ap + (((2 * s + hi) ^ (ra & 7)) << 4));
                    bf[mi][s] = *(const bf16x8*)(bp + (((2 * s + hi) ^ (rb & 7)) << 4));
                }
            }
            __builtin_amdgcn_s_setprio(1);
#pragma unroll
            for (int s = 0; s < 4; ++s) {
                acc[0][0] = MFMA32(af[0][s], bf[0][s], acc[0][0]);
                acc[0][1] = MFMA32(af[0][s], bf[1][s], acc[0][1]);
                acc[1][0] = MFMA32(af[1][s], bf[0][s], acc[1][0]);
                acc[1][1] = MFMA32(af[1][s], bf[1][s], acc[1][1]);
            }
            __builtin_amdgcn_s_setprio(0);
            asm volatile("s_waitcnt vmcnt(0)" ::: "memory");
            __builtin_amdgcn_s_barrier();
            asm volatile("" ::: "memory");
        }
    }
#undef STAGE

    // pin all pending LDS ops before reusing smem (rule #18)
    __builtin_amdgcn_sched_barrier(0);
    __syncthreads();

    // C/D layout (32x32, m74/m101): col = lane&31 (px), row = (reg&3)+8*(reg>>2)+4*hi (och)
    if (PHASE == 1) {
        // stage [128 px][128 och] bf16 (32 KB) into LDS, XOR-swizzled; flush contiguous NT
        __bf16* const ot = (__bf16*)smem;
#pragma unroll
        for (int mi = 0; mi < 2; ++mi)
#pragma unroll
            for (int j = 0; j < 2; ++j) {
                int px = wn + j * 32 + l31;
#pragma unroll
                for (int q2 = 0; q2 < 4; ++q2) {
                    int ob = (wo + mi * 32 + 8 * q2 + 4 * hi) * 2;  // byte in 256B row
                    union { __bf16 v[4]; uint2 u; } pk;
#pragma unroll
                    for (int r = 0; r < 4; ++r) {
                        float v = acc[mi][j][q2 * 4 + r];
                        pk.v[r] = (__bf16)((v > 0.f) ? v : 0.2f * v);
                    }
                    *(uint2*)((char*)ot + px * 256 + (ob ^ ((px & 7) << 4))) = pk.u;
                }
            }
        __syncthreads();
        // flush: 4 px per instr, 16 lanes x 16B = 256B contiguous per pixel
#pragma unroll
        for (int it = 0; it < 8; ++it) {
            int px = wv * 32 + it * 4 + (lane >> 4);
            u32x4 v = *(const u32x4*)((const char*)ot + px * 256 + (((lane & 15) * 16) ^ ((px & 7) << 4)));
            __builtin_nontemporal_store(v,
                (u32x4*)(outb + (((size_t)(b * 130) + yrow + 1) * 130 + px + 1) * 256 + om + (lane & 15) * 8));
        }
    } else {
        // NCHW f32: 32 lanes x 4B = contiguous 128B per och row, NT
#pragma unroll
        for (int mi = 0; mi < 2; ++mi)
#pragma unroll
            for (int j = 0; j < 2; ++j) {
                int n = wn + j * 32 + l31;
#pragma unroll
                for (int q2 = 0; q2 < 4; ++q2)
#pragma unroll
                    for (int r = 0; r < 4; ++r) {
                        int och = om + wo + mi * 32 + 8 * q2 + 4 * hi + r;
                        float v = acc[mi][j][q2 * 4 + r];
                        v = (v > 0.f) ? v : 0.2f * v;
                        __builtin_nontemporal_store(v,
                            &outf[((size_t)(b * 256 + och) * 128 + yrow) * 128 + n]);
                    }
            }
    }
}

extern "C" void kernel_launch(void* const* d_in, const int* in_sizes, int n_in,
                              void* d_out, int out_size, void* d_ws, size_t ws_size,
                              hipStream_t stream) {
    const float* x      = (const float*)d_in[0];
    const float* istyle = (const float*)d_in[1];
    const float* ws1    = (const float*)d_in[2];
    const float* bs1    = (const float*)d_in[3];
    const float* w1     = (const float*)d_in[4];
    const float* ws2    = (const float*)d_in[5];
    const float* bs2    = (const float*)d_in[6];
    const float* w2     = (const float*)d_in[7];
    float* out = (float*)d_out;

    char* ws = (char*)d_ws;
    __bf16* xu_p = (__bf16*)(ws);
    __bf16* y1_p = (__bf16*)(ws + 69222400);
    __bf16* wm   = (__bf16*)(ws + 138444800);
    float*  sbuf = (float*)(ws + 147881984);

    style_kernel<<<dim3(8, 2), 256, 0, stream>>>(istyle, ws1, bs1, ws2, bs2, sbuf);
    zeropad_kernel<<<dim3(65, 8, 2), 256, 0, stream>>>(xu_p, y1_p);
    upsample_kernel<<<dim3(128, 8), 256, 0, stream>>>(x, xu_p);
    modw_kernel<<<dim3(512), 256, 0, stream>>>(w1, sbuf, wm);
    conv_kernel<1><<<dim3(2048), 256, 0, stream>>>(xu_p, wm, nullptr, y1_p);
    modw_kernel<<<dim3(512), 256, 0, stream>>>(w2, sbuf + 2048, wm);
    conv_kernel<2><<<dim3(2048), 256, 0, stream>>>(y1_p, wm, out, nullptr);
}

// Round 12
// 379.545 us; speedup vs baseline: 1.2377x; 1.2377x over previous
//
#include <hip/hip_runtime.h>

typedef __bf16 bf16x8 __attribute__((ext_vector_type(8)));
typedef float f32x4 __attribute__((ext_vector_type(4)));

// ---------------- sizes ----------------
// B=8, LAT=512, CIN=F=256, Hin=Win=64, H=W=128, K=3
// ws layout (bytes):
//   xu_p NHWC bf16 [8][130][130][256] : off 0          size 69222400
//   y1_p NHWC bf16 [8][130][130][256] : off 69222400   size 69222400
//   wm   bf16 [8][256][9][256]        : off 138444800  size 9437184   (reused)
//   sbuf f32 [2][8][256]              : off 147881984  size 16384

#define GLDS(gsrc, ldst) __builtin_amdgcn_global_load_lds( \
    (const __attribute__((address_space(1))) unsigned int*)(gsrc), \
    (__attribute__((address_space(3))) unsigned int*)(ldst), 16, 0, 0)

#define MFMA(a, b, c) __builtin_amdgcn_mfma_f32_16x16x32_bf16((a), (b), (c), 0, 0, 0)

// ---------------- styles ----------------
__global__ void style_kernel(const float* __restrict__ istyle,
                             const float* __restrict__ ws1, const float* __restrict__ bs1,
                             const float* __restrict__ ws2, const float* __restrict__ bs2,
                             float* __restrict__ sbuf) {
    int b = blockIdx.x;
    int which = blockIdx.y;
    int c = threadIdx.x;
    const float* ws = which ? ws2 : ws1;
    const float* bs = which ? bs2 : bs1;
    __shared__ float st[512];
    for (int i = threadIdx.x; i < 512; i += 256) st[i] = istyle[b * 512 + i];
    __syncthreads();
    float acc = bs[c];
    const float* wr = ws + (size_t)c * 512;
    for (int l = 0; l < 512; ++l) acc += st[l] * wr[l];
    sbuf[((size_t)which * 8 + b) * 256 + c] = acc;
}

// ---------------- modulate + demodulate -> bf16 [b][o][tap][c] ----------------
// One wave per (b,o): lane covers 4 channels x 9 taps; shfl-xor wave reduce.
__global__ void modw_kernel(const float* __restrict__ w, const float* __restrict__ s,
                            __bf16* __restrict__ wm) {
    int wv = threadIdx.x >> 6, lane = threadIdx.x & 63;
    int idx = blockIdx.x * 4 + wv;      // 0..2047
    int b = idx >> 8, o = idx & 255;
    int c0 = lane * 4;
    const float* wr = w + ((size_t)o * 256 + c0) * 9;
    const float* sb = s + (size_t)b * 256 + c0;
    float v[36];
    float ss = 0.f;
#pragma unroll
    for (int cc = 0; cc < 4; ++cc) {
        float sm = sb[cc] + 1.0f;
#pragma unroll
        for (int t = 0; t < 9; ++t) {
            float x = wr[cc * 9 + t] * sm;
            v[cc * 9 + t] = x;
            ss += x * x;
        }
    }
#pragma unroll
    for (int off = 32; off > 0; off >>= 1) ss += __shfl_xor(ss, off);
    float d = rsqrtf(ss + 1e-8f);
    __bf16* wp = wm + ((size_t)(b * 256 + o) * 9) * 256 + c0;
#pragma unroll
    for (int t = 0; t < 9; ++t) {
        union { __bf16 h[4]; uint2 u; } pk;
#pragma unroll
        for (int cc = 0; cc < 4; ++cc) pk.h[cc] = (__bf16)(v[cc * 9 + t] * d);
        *(uint2*)(wp + (size_t)t * 256) = pk.u;
    }
}

// ---------------- zero the 1-pixel border ----------------
__global__ void zeropad_kernel(__bf16* __restrict__ xu, __bf16* __restrict__ y1) {
    int p0 = blockIdx.x * 8;
    int b  = blockIdx.y;
    __bf16* buf = blockIdx.z ? y1 : xu;
    int p = p0 + (threadIdx.x >> 5);
    if (p >= 516) return;
    int chunk = threadIdx.x & 31;
    int y, x;
    if (p < 130)      { y = 0;           x = p; }
    else if (p < 260) { y = 129;         x = p - 130; }
    else if (p < 388) { y = p - 260 + 1; x = 0; }
    else              { y = p - 388 + 1; x = 129; }
    uint4 z = make_uint4(0, 0, 0, 0);
    *(uint4*)(buf + (((size_t)b * 130 + y) * 130 + x) * 256 + chunk * 8) = z;
}

// ---------------- bilinear 2x upsample NCHW f32 -> padded NHWC bf16 ----------------
__global__ void upsample_kernel(const float* __restrict__ x, __bf16* __restrict__ xu) {
    int ct = blockIdx.x;
    int y  = blockIdx.y;
    int b  = blockIdx.z;
    int c0 = ct * 32;
    __shared__ float up[32 * 132];
    int tid = threadIdx.x;

    int j = y >> 1;
    int y0, y1; float wy0, wy1;
    if (y & 1) { y0 = j; y1 = (j + 1 < 64) ? j + 1 : 63; wy0 = 0.75f; wy1 = 0.25f; }
    else       { y0 = (j - 1 >= 0) ? j - 1 : 0; y1 = j; wy0 = 0.25f; wy1 = 0.75f; }

    int c  = tid >> 3;
    int xs = (tid & 7) * 16;
    const float* row0 = x + ((size_t)(b * 256 + c0 + c) * 64 + y0) * 64;
    const float* row1 = x + ((size_t)(b * 256 + c0 + c) * 64 + y1) * 64;
#pragma unroll
    for (int k = 0; k < 16; ++k) {
        int xo = xs + k;
        int i = xo >> 1;
        int x0, x1; float wx0, wx1;
        if (xo & 1) { x0 = i; x1 = (i + 1 < 64) ? i + 1 : 63; wx0 = 0.75f; wx1 = 0.25f; }
        else        { x0 = (i - 1 >= 0) ? i - 1 : 0; x1 = i; wx0 = 0.25f; wx1 = 0.75f; }
        float v0 = wx0 * row0[x0] + wx1 * row0[x1];
        float v1 = wx0 * row1[x0] + wx1 * row1[x1];
        up[c * 132 + xo] = wy0 * v0 + wy1 * v1;
    }
    __syncthreads();
    int xo = tid >> 1, half = tid & 1;
    union { __bf16 v[8]; uint4 u; } pk;
#pragma unroll
    for (int g = 0; g < 2; ++g) {
#pragma unroll
        for (int i = 0; i < 8; ++i)
            pk.v[i] = (__bf16)up[(half * 16 + g * 8 + i) * 132 + xo];
        *(uint4*)(xu + (((size_t)(b * 130) + y + 1) * 130 + xo + 1) * 256 + c0 + half * 16 + g * 8) = pk.u;
    }
}

// ---------------- implicit-GEMM modulated conv, 256x256 tile, 8-phase schedule ----------------
// R4 configuration (best measured: 151 us/conv, FETCH 44MB, 0 conflicts).
// K-order: c0-major, tap-minor. Counted vmcnt: (4) end ph1, (2) end ph3.
// PHASE 1 epilogue: LDS-transpose -> contiguous 512B/pixel NHWC stores.
template <int PHASE>
__global__ __launch_bounds__(512, 2) void conv_kernel(
    const __bf16* __restrict__ in,    // padded NHWC [8][130][130][256]
    const __bf16* __restrict__ wmall, // [8][256][9][256]
    float* __restrict__ outf,
    __bf16* __restrict__ outb) {
    __shared__ __attribute__((aligned(128))) char smem[131072];
    __bf16* const sA0 = (__bf16*)smem;             // [2][256*64]
    __bf16* const sB0 = (__bf16*)(smem + 65536);   // [2][256*64]
    const int tid  = threadIdx.x;
    const int bid  = blockIdx.x;
    // XCD-bijective swizzle: 512 blocks = 8 XCDs x 64; one batch per XCD.
    const int swz  = (bid & 7) * 64 + (bid >> 3);
    const int b    = swz >> 6;
    const int yt   = swz & 63;          // output row pair
    const int lane = tid & 63;
    const int wv   = tid >> 6;          // 0..7
    const int wo   = (wv >> 2) * 128;   // wave M offset
    const int wn   = (wv & 3) * 64;     // wave N offset
    const int arow = lane & 15;
    const int cgb  = lane >> 4;         // 0..3
    const int xA0  = (cgb ^ (arow & 7)) * 8;
    const int xA1  = xA0 ^ 32;
    // staging lane decomposition
    const int lr   = lane >> 3;
    const int lc   = lane & 7;
    const int swz8 = (lc ^ lr) * 8;
    const __bf16* wm_b = wmall + (size_t)b * 256 * 2304;

    size_t bOff[4], aOff[4];
#pragma unroll
    for (int q = 0; q < 4; ++q) {
        int r  = q * 64 + wv * 8 + lr;          // 0..255
        int pr = r >> 7, px = r & 127;
        bOff[q] = ((size_t)((b * 130 + yt * 2 + pr) * 130 + px)) * 256 + swz8;
        aOff[q] = (size_t)r * 2304 + swz8;
    }

    f32x4 acc[8][4] = {};
    bf16x8 bf[4][2];

    // prologue: stage K-tile 0 (tap=0, c0=0) into buffer 0
#pragma unroll
    for (int q = 0; q < 4; ++q) {
        GLDS(in + bOff[q],   sB0 + (q * 64 + wv * 8) * 64);
        GLDS(wm_b + aOff[q], sA0 + (q * 64 + wv * 8) * 64);
    }
    asm volatile("s_waitcnt vmcnt(0)" ::: "memory");
    __builtin_amdgcn_s_barrier();
    asm volatile("" ::: "memory");

    for (int t = 0; t < 36; ++t) {
        const __bf16* Ac = sA0 + (t & 1) * 16384;
        const __bf16* Bc = sB0 + (t & 1) * 16384;
        __bf16* An = sA0 + ((t + 1) & 1) * 16384;
        __bf16* Bn = sB0 + ((t + 1) & 1) * 16384;
        const bool st = (t < 35);
        const int nt   = t + 1;
        const int ncb  = nt / 9;
        const int ntap = nt - 9 * ncb;
        const int nc0  = ncb * 64;
        const int nky  = ntap / 3, nkx = ntap - 3 * nky;
        const size_t boff_t = (size_t)((nky * 130 + nkx) * 256 + nc0);
        const size_t aoff_t = (size_t)(ntap * 256 + nc0);

#define LOADA(qq, A00, A01, A10, A11)                                        \
        { const __bf16* ap0 = Ac + (wo + (2*(qq)) * 16 + arow) * 64;         \
          const __bf16* ap1 = Ac + (wo + (2*(qq)+1) * 16 + arow) * 64;       \
          A00 = *(const bf16x8*)(ap0 + xA0); A01 = *(const bf16x8*)(ap0 + xA1); \
          A10 = *(const bf16x8*)(ap1 + xA0); A11 = *(const bf16x8*)(ap1 + xA1); }

#define MFMAQ(M0, M1, A00, A01, A10, A11)                                    \
        _Pragma("unroll")                                                    \
        for (int j = 0; j < 4; ++j) {                                        \
            acc[M0][j] = MFMA(A00, bf[j][0], acc[M0][j]);                    \
            acc[M0][j] = MFMA(A01, bf[j][1], acc[M0][j]);                    \
            acc[M1][j] = MFMA(A10, bf[j][0], acc[M1][j]);                    \
            acc[M1][j] = MFMA(A11, bf[j][1], acc[M1][j]);                    \
        }

        // ---- phase 0 ----
        {
#pragma unroll
            for (int j = 0; j < 4; ++j) {
                const __bf16* bp = Bc + (wn + j * 16 + arow) * 64;
                bf[j][0] = *(const bf16x8*)(bp + xA0);
                bf[j][1] = *(const bf16x8*)(bp + xA1);
            }
            bf16x8 a00, a01, a10, a11;
            LOADA(0, a00, a01, a10, a11);
            if (st) {
                GLDS(in + bOff[0] + boff_t, Bn + (0 * 64 + wv * 8) * 64);
                GLDS(in + bOff[1] + boff_t, Bn + (1 * 64 + wv * 8) * 64);
            }
            __builtin_amdgcn_s_barrier();
            asm volatile("" ::: "memory");
            __builtin_amdgcn_s_setprio(1);
            MFMAQ(0, 1, a00, a01, a10, a11);
            __builtin_amdgcn_s_setprio(0);
            __builtin_amdgcn_s_barrier();
            asm volatile("" ::: "memory");
        }
        // ---- phase 1 ----
        {
            bf16x8 a00, a01, a10, a11;
            LOADA(1, a00, a01, a10, a11);
            if (st) {
                GLDS(in + bOff[2] + boff_t, Bn + (2 * 64 + wv * 8) * 64);
                GLDS(in + bOff[3] + boff_t, Bn + (3 * 64 + wv * 8) * 64);
            }
            __builtin_amdgcn_s_barrier();
            asm volatile("" ::: "memory");
            __builtin_amdgcn_s_setprio(1);
            MFMAQ(2, 3, a00, a01, a10, a11);
            __builtin_amdgcn_s_setprio(0);
            if (st) { asm volatile("s_waitcnt vmcnt(4)" ::: "memory"); }
            else    { asm volatile("s_waitcnt vmcnt(0)" ::: "memory"); }
            __builtin_amdgcn_s_barrier();
            asm volatile("" ::: "memory");
        }
        // ---- phase 2 ----
        {
            bf16x8 a00, a01, a10, a11;
            LOADA(2, a00, a01, a10, a11);
            if (st) {
                GLDS(wm_b + aOff[0] + aoff_t, An + (0 * 64 + wv * 8) * 64);
                GLDS(wm_b + aOff[2] + aoff_t, An + (2 * 64 + wv * 8) * 64);
            }
            __builtin_amdgcn_s_barrier();
            asm volatile("" ::: "memory");
            __builtin_amdgcn_s_setprio(1);
            MFMAQ(4, 5, a00, a01, a10, a11);
            __builtin_amdgcn_s_setprio(0);
            __builtin_amdgcn_s_barrier();
            asm volatile("" ::: "memory");
        }
        // ---- phase 3 ----
        {
            bf16x8 a00, a01, a10, a11;
            LOADA(3, a00, a01, a10, a11);
            if (st) {
                GLDS(wm_b + aOff[1] + aoff_t, An + (1 * 64 + wv * 8) * 64);
                GLDS(wm_b + aOff[3] + aoff_t, An + (3 * 64 + wv * 8) * 64);
            }
            __builtin_amdgcn_s_barrier();
            asm volatile("" ::: "memory");
            __builtin_amdgcn_s_setprio(1);
            MFMAQ(6, 7, a00, a01, a10, a11);
            __builtin_amdgcn_s_setprio(0);
            if (st) { asm volatile("s_waitcnt vmcnt(2)" ::: "memory"); }
            __builtin_amdgcn_s_barrier();
            asm volatile("" ::: "memory");
        }
#undef LOADA
#undef MFMAQ
    }

    // pin all pending LDS reads / MFMAs before reusing smem (rule #18)
    __builtin_amdgcn_sched_barrier(0);
    __syncthreads();

    if (PHASE == 1) {
        // stage output tile [n=256 px][och=256] bf16 into LDS, XOR-swizzled rows
        __bf16* const ot = (__bf16*)smem;
        const int al = lane & 15;
        const int cg = lane >> 4;
#pragma unroll
        for (int m = 0; m < 8; ++m) {
#pragma unroll
            for (int j = 0; j < 4; ++j) {
                int n   = wn + j * 16 + al;
                int och = wo + m * 16 + cg * 4;
                union { __bf16 v[4]; uint2 u; } pk;
#pragma unroll
                for (int r = 0; r < 4; ++r) {
                    float v = acc[m][j][r];
                    pk.v[r] = (__bf16)((v > 0.f) ? v : 0.2f * v);
                }
                *(uint2*)((char*)ot + n * 512 + ((och * 2) ^ ((n & 7) << 4))) = pk.u;
            }
        }
        __syncthreads();
        // flush: per wave 32 pixels, 2 pixels/iter, contiguous 512B per pixel
        const int half = lane >> 5;
        const int l32  = lane & 31;
#pragma unroll
        for (int p = 0; p < 16; ++p) {
            int n  = wv * 32 + p * 2 + half;
            int pr = n >> 7, px = n & 127;
            uint4 v = *(const uint4*)((const char*)ot + n * 512 + ((l32 * 16) ^ ((n & 7) << 4)));
            *(uint4*)(outb + (((size_t)(b * 130) + yt * 2 + pr + 1) * 130 + px + 1) * 256 + l32 * 8) = v;
        }
    } else {
        // NCHW f32: 16 lanes x 4B = contiguous 64B lines
#pragma unroll
        for (int m = 0; m < 8; ++m) {
#pragma unroll
            for (int j = 0; j < 4; ++j) {
                int o_base = wo + m * 16 + (lane >> 4) * 4;
                int n      = wn + j * 16 + (lane & 15);
                int pr = n >> 7, px = n & 127;
#pragma unroll
                for (int r = 0; r < 4; ++r) {
                    float v = acc[m][j][r];
                    v = (v > 0.f) ? v : 0.2f * v;
                    outf[((size_t)(b * 256 + o_base + r) * 128 + yt * 2 + pr) * 128 + px] = v;
                }
            }
        }
    }
}

extern "C" void kernel_launch(void* const* d_in, const int* in_sizes, int n_in,
                              void* d_out, int out_size, void* d_ws, size_t ws_size,
                              hipStream_t stream) {
    const float* x      = (const float*)d_in[0];
    const float* istyle = (const float*)d_in[1];
    const float* ws1    = (const float*)d_in[2];
    const float* bs1    = (const float*)d_in[3];
    const float* w1     = (const float*)d_in[4];
    const float* ws2    = (const float*)d_in[5];
    const float* bs2    = (const float*)d_in[6];
    const float* w2     = (const float*)d_in[7];
    float* out = (float*)d_out;

    char* ws = (char*)d_ws;
    __bf16* xu_p = (__bf16*)(ws);
    __bf16* y1_p = (__bf16*)(ws + 69222400);
    __bf16* wm   = (__bf16*)(ws + 138444800);
    float*  sbuf = (float*)(ws + 147881984);

    style_kernel<<<dim3(8, 2), 256, 0, stream>>>(istyle, ws1, bs1, ws2, bs2, sbuf);
    zeropad_kernel<<<dim3(65, 8, 2), 256, 0, stream>>>(xu_p, y1_p);
    upsample_kernel<<<dim3(8, 128, 8), 256, 0, stream>>>(x, xu_p);
    modw_kernel<<<dim3(512), 256, 0, stream>>>(w1, sbuf, wm);
    conv_kernel<1><<<dim3(512), 512, 0, stream>>>(xu_p, wm, nullptr, y1_p);
    modw_kernel<<<dim3(512), 256, 0, stream>>>(w2, sbuf + 2048, wm);
    conv_kernel<2><<<dim3(512), 512, 0, stream>>>(y1_p, wm, out, nullptr);
}

// Round 13
// 370.092 us; speedup vs baseline: 1.2694x; 1.0255x over previous
//
#include <hip/hip_runtime.h>

typedef __bf16 bf16x8 __attribute__((ext_vector_type(8)));
typedef float f32x4 __attribute__((ext_vector_type(4)));

// ---------------- sizes ----------------
// B=8, LAT=512, CIN=F=256, Hin=Win=64, H=W=128, K=3
// ws layout (bytes):
//   xu_p NHWC bf16 [8][130][130][256] : off 0          size 69222400
//   y1_p NHWC bf16 [8][130][130][256] : off 69222400   size 69222400
//   wm1  bf16 [8][256][9][256]        : off 138444800  size 9437184
//   sbuf f32 [2][8][256]              : off 147881984  size 16384
//   wm2  bf16 [8][256][9][256]        : off 147898368  size 9437184  (only if ws_size allows)

#define GLDS(gsrc, ldst) __builtin_amdgcn_global_load_lds( \
    (const __attribute__((address_space(1))) unsigned int*)(gsrc), \
    (__attribute__((address_space(3))) unsigned int*)(ldst), 16, 0, 0)

#define MFMA(a, b, c) __builtin_amdgcn_mfma_f32_16x16x32_bf16((a), (b), (c), 0, 0, 0)

// ---------------- styles ----------------
__global__ void style_kernel(const float* __restrict__ istyle,
                             const float* __restrict__ ws1, const float* __restrict__ bs1,
                             const float* __restrict__ ws2, const float* __restrict__ bs2,
                             float* __restrict__ sbuf) {
    int b = blockIdx.x;
    int which = blockIdx.y;
    int c = threadIdx.x;
    const float* ws = which ? ws2 : ws1;
    const float* bs = which ? bs2 : bs1;
    __shared__ float st[512];
    for (int i = threadIdx.x; i < 512; i += 256) st[i] = istyle[b * 512 + i];
    __syncthreads();
    float acc = bs[c];
    const float* wr = ws + (size_t)c * 512;
    for (int l = 0; l < 512; ++l) acc += st[l] * wr[l];
    sbuf[((size_t)which * 8 + b) * 256 + c] = acc;
}

// ---------------- modw device body: one wave per (b,o) ----------------
__device__ __forceinline__ void modw_body(int idx, int lane,
                                          const float* __restrict__ w,
                                          const float* __restrict__ s,
                                          __bf16* __restrict__ wm) {
    int b = idx >> 8, o = idx & 255;
    int c0 = lane * 4;
    const float* wr = w + ((size_t)o * 256 + c0) * 9;
    const float* sb = s + (size_t)b * 256 + c0;
    float v[36];
    float ss = 0.f;
#pragma unroll
    for (int cc = 0; cc < 4; ++cc) {
        float sm = sb[cc] + 1.0f;
#pragma unroll
        for (int t = 0; t < 9; ++t) {
            float x = wr[cc * 9 + t] * sm;
            v[cc * 9 + t] = x;
            ss += x * x;
        }
    }
#pragma unroll
    for (int off = 32; off > 0; off >>= 1) ss += __shfl_xor(ss, off);
    float d = rsqrtf(ss + 1e-8f);
    __bf16* wp = wm + ((size_t)(b * 256 + o) * 9) * 256 + c0;
#pragma unroll
    for (int t = 0; t < 9; ++t) {
        union { __bf16 h[4]; uint2 u; } pk;
#pragma unroll
        for (int cc = 0; cc < 4; ++cc) pk.h[cc] = (__bf16)(v[cc * 9 + t] * d);
        *(uint2*)(wp + (size_t)t * 256) = pk.u;
    }
}

// ---------------- standalone modw (fallback path) ----------------
__global__ void modw_kernel(const float* __restrict__ w, const float* __restrict__ s,
                            __bf16* __restrict__ wm) {
    int wv = threadIdx.x >> 6, lane = threadIdx.x & 63;
    modw_body(blockIdx.x * 4 + wv, lane, w, s, wm);
}

// ---------------- fused prep: upsample + zeropad + modw1 (+ modw2) ----------------
// flat grid partition: [0,8192) upsample; [8192,9232) zeropad; [9232,9744) modw1;
// [9744,10256) modw2 (launched only when ws_size permits a separate wm2 buffer).
__global__ __launch_bounds__(256) void prep_kernel(
    const float* __restrict__ x, __bf16* __restrict__ xu, __bf16* __restrict__ y1,
    const float* __restrict__ w1, const float* __restrict__ w2,
    const float* __restrict__ sbuf,
    __bf16* __restrict__ wm1, __bf16* __restrict__ wm2) {
    __shared__ float up[32 * 132];
    const int i   = blockIdx.x;
    const int tid = threadIdx.x;

    if (i < 8192) {
        // ---- bilinear 2x upsample NCHW f32 -> padded NHWC bf16 ----
        int ct = i & 7;
        int y  = (i >> 3) & 127;
        int b  = i >> 10;
        int c0 = ct * 32;

        int j = y >> 1;
        int y0, y1r; float wy0, wy1;
        if (y & 1) { y0 = j; y1r = (j + 1 < 64) ? j + 1 : 63; wy0 = 0.75f; wy1 = 0.25f; }
        else       { y0 = (j - 1 >= 0) ? j - 1 : 0; y1r = j; wy0 = 0.25f; wy1 = 0.75f; }

        int c  = tid >> 3;
        int xs = (tid & 7) * 16;
        const float* row0 = x + ((size_t)(b * 256 + c0 + c) * 64 + y0) * 64;
        const float* row1 = x + ((size_t)(b * 256 + c0 + c) * 64 + y1r) * 64;
#pragma unroll
        for (int k = 0; k < 16; ++k) {
            int xo = xs + k;
            int ii = xo >> 1;
            int x0, x1; float wx0, wx1;
            if (xo & 1) { x0 = ii; x1 = (ii + 1 < 64) ? ii + 1 : 63; wx0 = 0.75f; wx1 = 0.25f; }
            else        { x0 = (ii - 1 >= 0) ? ii - 1 : 0; x1 = ii; wx0 = 0.25f; wx1 = 0.75f; }
            float v0 = wx0 * row0[x0] + wx1 * row0[x1];
            float v1 = wx0 * row1[x0] + wx1 * row1[x1];
            up[c * 132 + xo] = wy0 * v0 + wy1 * v1;
        }
        __syncthreads();
        int xo = tid >> 1, half = tid & 1;
        union { __bf16 v[8]; uint4 u; } pk;
#pragma unroll
        for (int g = 0; g < 2; ++g) {
#pragma unroll
            for (int k = 0; k < 8; ++k)
                pk.v[k] = (__bf16)up[(half * 16 + g * 8 + k) * 132 + xo];
            *(uint4*)(xu + (((size_t)(b * 130) + y + 1) * 130 + xo + 1) * 256 + c0 + half * 16 + g * 8) = pk.u;
        }
    } else if (i < 9232) {
        // ---- zero the 1-pixel border of both padded buffers ----
        int jj = i - 8192;               // 0..1039
        int p0 = (jj % 65) * 8;
        int b  = (jj / 65) & 7;
        __bf16* buf = (jj >= 520) ? y1 : xu;
        int p = p0 + (tid >> 5);
        if (p >= 516) return;
        int chunk = tid & 31;
        int yy, xx;
        if (p < 130)      { yy = 0;           xx = p; }
        else if (p < 260) { yy = 129;         xx = p - 130; }
        else if (p < 388) { yy = p - 260 + 1; xx = 0; }
        else              { yy = p - 388 + 1; xx = 129; }
        uint4 z = make_uint4(0, 0, 0, 0);
        *(uint4*)(buf + (((size_t)b * 130 + yy) * 130 + xx) * 256 + chunk * 8) = z;
    } else if (i < 9744) {
        // ---- modw1 ----
        int wv = tid >> 6, lane = tid & 63;
        modw_body((i - 9232) * 4 + wv, lane, w1, sbuf, wm1);
    } else {
        // ---- modw2 (separate wm2 buffer) ----
        int wv = tid >> 6, lane = tid & 63;
        modw_body((i - 9744) * 4 + wv, lane, w2, sbuf + 2048, wm2);
    }
}

// ---------------- implicit-GEMM modulated conv, 256x256 tile, 8-phase schedule ----------------
// R4/R12 configuration (measured stable: 151 us/conv, MfmaUtil ~45%, FETCH 44MB, 0 conflicts).
// K-order: c0-major, tap-minor. Counted vmcnt: (4) end ph1, (2) end ph3.
// PHASE 1 epilogue: LDS-transpose -> contiguous 512B/pixel NHWC stores.
template <int PHASE>
__global__ __launch_bounds__(512, 2) void conv_kernel(
    const __bf16* __restrict__ in,    // padded NHWC [8][130][130][256]
    const __bf16* __restrict__ wmall, // [8][256][9][256]
    float* __restrict__ outf,
    __bf16* __restrict__ outb) {
    __shared__ __attribute__((aligned(128))) char smem[131072];
    __bf16* const sA0 = (__bf16*)smem;             // [2][256*64]
    __bf16* const sB0 = (__bf16*)(smem + 65536);   // [2][256*64]
    const int tid  = threadIdx.x;
    const int bid  = blockIdx.x;
    // XCD-bijective swizzle: 512 blocks = 8 XCDs x 64; one batch per XCD.
    const int swz  = (bid & 7) * 64 + (bid >> 3);
    const int b    = swz >> 6;
    const int yt   = swz & 63;          // output row pair
    const int lane = tid & 63;
    const int wv   = tid >> 6;          // 0..7
    const int wo   = (wv >> 2) * 128;   // wave M offset
    const int wn   = (wv & 3) * 64;     // wave N offset
    const int arow = lane & 15;
    const int cgb  = lane >> 4;         // 0..3
    const int xA0  = (cgb ^ (arow & 7)) * 8;
    const int xA1  = xA0 ^ 32;
    // staging lane decomposition
    const int lr   = lane >> 3;
    const int lc   = lane & 7;
    const int swz8 = (lc ^ lr) * 8;
    const __bf16* wm_b = wmall + (size_t)b * 256 * 2304;

    size_t bOff[4], aOff[4];
#pragma unroll
    for (int q = 0; q < 4; ++q) {
        int r  = q * 64 + wv * 8 + lr;          // 0..255
        int pr = r >> 7, px = r & 127;
        bOff[q] = ((size_t)((b * 130 + yt * 2 + pr) * 130 + px)) * 256 + swz8;
        aOff[q] = (size_t)r * 2304 + swz8;
    }

    f32x4 acc[8][4] = {};
    bf16x8 bf[4][2];

    // prologue: stage K-tile 0 (tap=0, c0=0) into buffer 0
#pragma unroll
    for (int q = 0; q < 4; ++q) {
        GLDS(in + bOff[q],   sB0 + (q * 64 + wv * 8) * 64);
        GLDS(wm_b + aOff[q], sA0 + (q * 64 + wv * 8) * 64);
    }
    asm volatile("s_waitcnt vmcnt(0)" ::: "memory");
    __builtin_amdgcn_s_barrier();
    asm volatile("" ::: "memory");

    for (int t = 0; t < 36; ++t) {
        const __bf16* Ac = sA0 + (t & 1) * 16384;
        const __bf16* Bc = sB0 + (t & 1) * 16384;
        __bf16* An = sA0 + ((t + 1) & 1) * 16384;
        __bf16* Bn = sB0 + ((t + 1) & 1) * 16384;
        const bool st = (t < 35);
        const int nt   = t + 1;
        const int ncb  = nt / 9;
        const int ntap = nt - 9 * ncb;
        const int nc0  = ncb * 64;
        const int nky  = ntap / 3, nkx = ntap - 3 * nky;
        const size_t boff_t = (size_t)((nky * 130 + nkx) * 256 + nc0);
        const size_t aoff_t = (size_t)(ntap * 256 + nc0);

#define LOADA(qq, A00, A01, A10, A11)                                        \
        { const __bf16* ap0 = Ac + (wo + (2*(qq)) * 16 + arow) * 64;         \
          const __bf16* ap1 = Ac + (wo + (2*(qq)+1) * 16 + arow) * 64;       \
          A00 = *(const bf16x8*)(ap0 + xA0); A01 = *(const bf16x8*)(ap0 + xA1); \
          A10 = *(const bf16x8*)(ap1 + xA0); A11 = *(const bf16x8*)(ap1 + xA1); }

#define MFMAQ(M0, M1, A00, A01, A10, A11)                                    \
        _Pragma("unroll")                                                    \
        for (int j = 0; j < 4; ++j) {                                        \
            acc[M0][j] = MFMA(A00, bf[j][0], acc[M0][j]);                    \
            acc[M0][j] = MFMA(A01, bf[j][1], acc[M0][j]);                    \
            acc[M1][j] = MFMA(A10, bf[j][0], acc[M1][j]);                    \
            acc[M1][j] = MFMA(A11, bf[j][1], acc[M1][j]);                    \
        }

        // ---- phase 0 ----
        {
#pragma unroll
            for (int j = 0; j < 4; ++j) {
                const __bf16* bp = Bc + (wn + j * 16 + arow) * 64;
                bf[j][0] = *(const bf16x8*)(bp + xA0);
                bf[j][1] = *(const bf16x8*)(bp + xA1);
            }
            bf16x8 a00, a01, a10, a11;
            LOADA(0, a00, a01, a10, a11);
            if (st) {
                GLDS(in + bOff[0] + boff_t, Bn + (0 * 64 + wv * 8) * 64);
                GLDS(in + bOff[1] + boff_t, Bn + (1 * 64 + wv * 8) * 64);
            }
            __builtin_amdgcn_s_barrier();
            asm volatile("" ::: "memory");
            __builtin_amdgcn_s_setprio(1);
            MFMAQ(0, 1, a00, a01, a10, a11);
            __builtin_amdgcn_s_setprio(0);
            __builtin_amdgcn_s_barrier();
            asm volatile("" ::: "memory");
        }
        // ---- phase 1 ----
        {
            bf16x8 a00, a01, a10, a11;
            LOADA(1, a00, a01, a10, a11);
            if (st) {
                GLDS(in + bOff[2] + boff_t, Bn + (2 * 64 + wv * 8) * 64);
                GLDS(in + bOff[3] + boff_t, Bn + (3 * 64 + wv * 8) * 64);
            }
            __builtin_amdgcn_s_barrier();
            asm volatile("" ::: "memory");
            __builtin_amdgcn_s_setprio(1);
            MFMAQ(2, 3, a00, a01, a10, a11);
            __builtin_amdgcn_s_setprio(0);
            if (st) { asm volatile("s_waitcnt vmcnt(4)" ::: "memory"); }
            else    { asm volatile("s_waitcnt vmcnt(0)" ::: "memory"); }
            __builtin_amdgcn_s_barrier();
            asm volatile("" ::: "memory");
        }
        // ---- phase 2 ----
        {
            bf16x8 a00, a01, a10, a11;
            LOADA(2, a00, a01, a10, a11);
            if (st) {
                GLDS(wm_b + aOff[0] + aoff_t, An + (0 * 64 + wv * 8) * 64);
                GLDS(wm_b + aOff[2] + aoff_t, An + (2 * 64 + wv * 8) * 64);
            }
            __builtin_amdgcn_s_barrier();
            asm volatile("" ::: "memory");
            __builtin_amdgcn_s_setprio(1);
            MFMAQ(4, 5, a00, a01, a10, a11);
            __builtin_amdgcn_s_setprio(0);
            __builtin_amdgcn_s_barrier();
            asm volatile("" ::: "memory");
        }
        // ---- phase 3 ----
        {
            bf16x8 a00, a01, a10, a11;
            LOADA(3, a00, a01, a10, a11);
            if (st) {
                GLDS(wm_b + aOff[1] + aoff_t, An + (1 * 64 + wv * 8) * 64);
                GLDS(wm_b + aOff[3] + aoff_t, An + (3 * 64 + wv * 8) * 64);
            }
            __builtin_amdgcn_s_barrier();
            asm volatile("" ::: "memory");
            __builtin_amdgcn_s_setprio(1);
            MFMAQ(6, 7, a00, a01, a10, a11);
            __builtin_amdgcn_s_setprio(0);
            if (st) { asm volatile("s_waitcnt vmcnt(2)" ::: "memory"); }
            __builtin_amdgcn_s_barrier();
            asm volatile("" ::: "memory");
        }
#undef LOADA
#undef MFMAQ
    }

    // pin all pending LDS reads / MFMAs before reusing smem (rule #18)
    __builtin_amdgcn_sched_barrier(0);
    __syncthreads();

    if (PHASE == 1) {
        // stage output tile [n=256 px][och=256] bf16 into LDS, XOR-swizzled rows
        __bf16* const ot = (__bf16*)smem;
        const int al = lane & 15;
        const int cg = lane >> 4;
#pragma unroll
        for (int m = 0; m < 8; ++m) {
#pragma unroll
            for (int j = 0; j < 4; ++j) {
                int n   = wn + j * 16 + al;
                int och = wo + m * 16 + cg * 4;
                union { __bf16 v[4]; uint2 u; } pk;
#pragma unroll
                for (int r = 0; r < 4; ++r) {
                    float v = acc[m][j][r];
                    pk.v[r] = (__bf16)((v > 0.f) ? v : 0.2f * v);
                }
                *(uint2*)((char*)ot + n * 512 + ((och * 2) ^ ((n & 7) << 4))) = pk.u;
            }
        }
        __syncthreads();
        // flush: per wave 32 pixels, 2 pixels/iter, contiguous 512B per pixel
        const int half = lane >> 5;
        const int l32  = lane & 31;
#pragma unroll
        for (int p = 0; p < 16; ++p) {
            int n  = wv * 32 + p * 2 + half;
            int pr = n >> 7, px = n & 127;
            uint4 v = *(const uint4*)((const char*)ot + n * 512 + ((l32 * 16) ^ ((n & 7) << 4)));
            *(uint4*)(outb + (((size_t)(b * 130) + yt * 2 + pr + 1) * 130 + px + 1) * 256 + l32 * 8) = v;
        }
    } else {
        // NCHW f32: 16 lanes x 4B = contiguous 64B lines
#pragma unroll
        for (int m = 0; m < 8; ++m) {
#pragma unroll
            for (int j = 0; j < 4; ++j) {
                int o_base = wo + m * 16 + (lane >> 4) * 4;
                int n      = wn + j * 16 + (lane & 15);
                int pr = n >> 7, px = n & 127;
#pragma unroll
                for (int r = 0; r < 4; ++r) {
                    float v = acc[m][j][r];
                    v = (v > 0.f) ? v : 0.2f * v;
                    outf[((size_t)(b * 256 + o_base + r) * 128 + yt * 2 + pr) * 128 + px] = v;
                }
            }
        }
    }
}

extern "C" void kernel_launch(void* const* d_in, const int* in_sizes, int n_in,
                              void* d_out, int out_size, void* d_ws, size_t ws_size,
                              hipStream_t stream) {
    const float* x      = (const float*)d_in[0];
    const float* istyle = (const float*)d_in[1];
    const float* ws1    = (const float*)d_in[2];
    const float* bs1    = (const float*)d_in[3];
    const float* w1     = (const float*)d_in[4];
    const float* ws2    = (const float*)d_in[5];
    const float* bs2    = (const float*)d_in[6];
    const float* w2     = (const float*)d_in[7];
    float* out = (float*)d_out;

    char* ws = (char*)d_ws;
    __bf16* xu_p = (__bf16*)(ws);
    __bf16* y1_p = (__bf16*)(ws + 69222400);
    __bf16* wm1  = (__bf16*)(ws + 138444800);
    float*  sbuf = (float*)(ws + 147881984);
    // optional separate wm2 (needs 157335552 bytes total)
    const bool sep = (ws_size >= 157335552ull);
    __bf16* wm2 = sep ? (__bf16*)(ws + 147898368) : wm1;

    style_kernel<<<dim3(8, 2), 256, 0, stream>>>(istyle, ws1, bs1, ws2, bs2, sbuf);
    // fused prep: upsample + zeropad + modw1 (+ modw2 when sep)
    prep_kernel<<<dim3(sep ? 10256 : 9744), 256, 0, stream>>>(
        x, xu_p, y1_p, w1, w2, sbuf, wm1, wm2);
    conv_kernel<1><<<dim3(512), 512, 0, stream>>>(xu_p, wm1, nullptr, y1_p);
    if (!sep)
        modw_kernel<<<dim3(512), 256, 0, stream>>>(w2, sbuf + 2048, wm1);
    conv_kernel<2><<<dim3(512), 512, 0, stream>>>(y1_p, wm2, out, nullptr);
}